// Round 10
// baseline (201.442 us; speedup 1.0000x reference)
//
#include <hip/hip_runtime.h>

#define VOCAB 5000
#define TTOK  16            // tokens per tile (64B of each W row, read-once)
#define JCH   2500          // output cols per chunk -> 10KB write/visit; 2 exact chunks
#define NFULL 9             // 2500 = 9*256 + 196
#define REMLN 49            // 196/4 lanes in remainder store

typedef float f32x4 __attribute__((ext_vector_type(4)));

// ---------------------------------------------------------------------------
// Counting sort of positions by token id (packed: (pos << 13) | token).
// ---------------------------------------------------------------------------
__global__ void zero_kernel(int* __restrict__ ptr, int n) {
    int i = blockIdx.x * blockDim.x + threadIdx.x;
    if (i < n) ptr[i] = 0;
}

__global__ void hist_kernel(const int* __restrict__ x, int* __restrict__ counts, int n) {
    int i = blockIdx.x * blockDim.x + threadIdx.x;
    if (i < n) atomicAdd(&counts[x[i]], 1);
}

// Single-block exclusive scan over VOCAB counters -> offs[0..VOCAB].
__global__ void scan_kernel(const int* __restrict__ counts, int* __restrict__ offs) {
    __shared__ int part[1024];
    const int tid = threadIdx.x;
    const int base = tid * 5;               // 1024*5 = 5120 >= 5000
    int local[5];
    int sum = 0;
#pragma unroll
    for (int k = 0; k < 5; ++k) {
        int idx = base + k;
        int v = (idx < VOCAB) ? counts[idx] : 0;
        local[k] = sum;
        sum += v;
    }
    part[tid] = sum;
    __syncthreads();
    for (int off = 1; off < 1024; off <<= 1) {
        int v = 0;
        if (tid >= off) v = part[tid - off];
        __syncthreads();
        if (tid >= off) part[tid] += v;
        __syncthreads();
    }
    const int prev = (tid > 0) ? part[tid - 1] : 0;
#pragma unroll
    for (int k = 0; k < 5; ++k) {
        int idx = base + k;
        if (idx < VOCAB) offs[idx] = prev + local[k];
    }
    if (tid == 1023) offs[VOCAB] = part[1023];
}

__global__ void scatter_kernel(const int* __restrict__ x, const int* __restrict__ offs,
                               int* __restrict__ cursor, int* __restrict__ sorted_pk, int n) {
    int i = blockIdx.x * blockDim.x + threadIdx.x;
    if (i < n) {
        int t = x[i];
        int d = atomicAdd(&cursor[t], 1);
        sorted_pk[offs[t] + d] = (i << 13) | t;   // pos (15b) | token (13b)
    }
}

// ---------------------------------------------------------------------------
// Fused transpose + broadcast gather.
// Block (cidx, tidx): W cols j0..j0+2499 (output cols) x tokens t0..t0+15.
// LDS tile = 16 x 2500 floats = 156.25 KiB (1 block/CU, 16 waves).
// Load: coalesced 64B row-segments of W, read exactly once device-wide.
// Store: one position per wave per iteration, 10KB contiguous NT write
// (9 full 1KB wave-stores + 49-lane remainder); pk prefetched one iter ahead.
// Chunk-size curve (R5..R9): 2KB=199us, 5KB=194, 8KB=187 -> push to 10KB.
// NT stores: R6 vs R8 A/B showed NT worth ~18us on this write stream.
// ---------------------------------------------------------------------------
__global__ __launch_bounds__(1024) void fused_gather_kernel(
        const float* __restrict__ W,
        const int* __restrict__ offs,
        const int* __restrict__ sorted_pk,
        float* __restrict__ out) {
    __shared__ float tileT[TTOK][JCH];        // [token][col], 156.25 KiB
    const int j0 = blockIdx.x * JCH;          // 0 or 2500; jcnt == JCH always
    const int t0 = blockIdx.y * TTOK;
    const int tcnt = min(TTOK, VOCAB - t0);   // 16 or 8
    const int tid = threadIdx.x;

    const int begin = offs[t0];
    const int end   = offs[t0 + tcnt];
    if (begin == end) return;                 // no positions use these tokens

    // --- load tile, transposed: tileT[token][col] ---
    const int nc4   = tcnt >> 2;              // f32x4 chunks across tokens: 4 or 2
    const int csh   = (tcnt == TTOK) ? 2 : 1;
    const int cmask = nc4 - 1;
    const int total = JCH * nc4;
    for (int idx = tid; idx < total; idx += 1024) {
        const int jr = idx >> csh;
        const int c  = idx & cmask;
        f32x4 v = *reinterpret_cast<const f32x4*>(
            W + (size_t)(j0 + jr) * VOCAB + t0 + c * 4);
        tileT[c * 4 + 0][jr] = v.x;
        tileT[c * 4 + 1][jr] = v.y;
        tileT[c * 4 + 2][jr] = v.z;
        tileT[c * 4 + 3][jr] = v.w;
    }
    __syncthreads();

    // --- broadcast write: 16 waves, one position per wave per iteration ---
    const int wid  = tid >> 6;                // 0..15
    const int lane = tid & 63;
    const int f0 = lane * 4;                  // 0..252

    int i = begin + wid;
    if (i >= end) return;
    int pk = sorted_pk[i];
    for (;;) {
        const int inext = i + 16;
        int pk_next = 0;
        if (inext < end) pk_next = sorted_pk[inext];   // prefetch next position

        const int p  = pk >> 13;
        const int tt = (pk & 8191) - t0;
        const float* __restrict__ srow = &tileT[tt][0];
        float* __restrict__ drow = out + (size_t)p * VOCAB + j0;
#pragma unroll
        for (int s = 0; s < NFULL; ++s) {
            f32x4 v = *reinterpret_cast<const f32x4*>(srow + f0 + s * 256);
            __builtin_nontemporal_store(
                v, reinterpret_cast<f32x4*>(drow + f0 + s * 256));
        }
        if (lane < REMLN) {
            f32x4 v = *reinterpret_cast<const f32x4*>(srow + f0 + NFULL * 256);
            __builtin_nontemporal_store(
                v, reinterpret_cast<f32x4*>(drow + f0 + NFULL * 256));
        }
        if (inext >= end) break;
        i = inext;
        pk = pk_next;
    }
}

// ---------------------------------------------------------------------------
// Fallback (ws too small): direct column gather, correct but strided reads.
// ---------------------------------------------------------------------------
__global__ void gather_cols_kernel(const float* __restrict__ W,
                                   const int* __restrict__ idx,
                                   float* __restrict__ out) {
    const int p = blockIdx.x;
    const int token = idx[p];
    for (int v = threadIdx.x; v < VOCAB; v += blockDim.x)
        out[(size_t)p * VOCAB + v] = W[(size_t)v * VOCAB + token];
}

extern "C" void kernel_launch(void* const* d_in, const int* in_sizes, int n_in,
                              void* d_out, int out_size, void* d_ws, size_t ws_size,
                              hipStream_t stream) {
    const int*   x = (const int*)d_in[0];     // [B*T] token ids
    const float* W = (const float*)d_in[1];   // [VOCAB, VOCAB] fp32
    float* out = (float*)d_out;               // [B*T, VOCAB] fp32
    const int npos = in_sizes[0];             // 32768

    // ws layout: counts[V] | cursor[V] | offs[V+1] | sorted_pk[npos]
    int* counts = (int*)d_ws;
    int* cursor = counts + VOCAB;
    int* offs   = cursor + VOCAB;
    int* sorted = offs + VOCAB + 1;
    const size_t need = (size_t)(3 * VOCAB + 1 + npos) * sizeof(int);

    if (ws_size >= need) {
        zero_kernel<<<(2 * VOCAB + 255) / 256, 256, 0, stream>>>(counts, 2 * VOCAB);
        hist_kernel<<<(npos + 255) / 256, 256, 0, stream>>>(x, counts, npos);
        scan_kernel<<<1, 1024, 0, stream>>>(counts, offs);
        scatter_kernel<<<(npos + 255) / 256, 256, 0, stream>>>(x, offs, cursor, sorted, npos);
        dim3 grid(2, (VOCAB + TTOK - 1) / TTOK);   // 2 x 313 = 626 blocks
        fused_gather_kernel<<<grid, 1024, 0, stream>>>(W, offs, sorted, out);
    } else {
        gather_cols_kernel<<<npos, 256, 0, stream>>>(W, x, out);
    }
}

// Round 11
// 194.010 us; speedup vs baseline: 1.0383x; 1.0383x over previous
//
#include <hip/hip_runtime.h>

#define VOCAB 5000
#define TTOK  16            // tokens per y-tile (64B of each W row, read-once)
#define TSUB  8             // tokens per LDS sub-tile (double-buffered)
#define JCH   2048          // output cols per chunk -> 8KB contiguous NT write/visit

typedef float f32x4 __attribute__((ext_vector_type(4)));
typedef int   i32x4 __attribute__((ext_vector_type(4)));

// ---------------------------------------------------------------------------
// Counting sort of positions by token id (packed: (pos << 13) | token).
// counts/cursor zeroed via hipMemsetAsync (no zero kernel).
// ---------------------------------------------------------------------------
__global__ void hist_kernel(const int* __restrict__ x, int* __restrict__ counts, int n) {
    int i = blockIdx.x * blockDim.x + threadIdx.x;
    int base = i * 4;
    if (base + 3 < n) {
        i32x4 v = *reinterpret_cast<const i32x4*>(x + base);
        atomicAdd(&counts[v.x], 1);
        atomicAdd(&counts[v.y], 1);
        atomicAdd(&counts[v.z], 1);
        atomicAdd(&counts[v.w], 1);
    } else {
        for (int k = base; k < n; ++k) atomicAdd(&counts[x[k]], 1);
    }
}

// Single-block exclusive scan over VOCAB counters -> offs[0..VOCAB].
__global__ void scan_kernel(const int* __restrict__ counts, int* __restrict__ offs) {
    __shared__ int part[1024];
    const int tid = threadIdx.x;
    const int base = tid * 5;               // 1024*5 = 5120 >= 5000
    int local[5];
    int sum = 0;
#pragma unroll
    for (int k = 0; k < 5; ++k) {
        int idx = base + k;
        int v = (idx < VOCAB) ? counts[idx] : 0;
        local[k] = sum;
        sum += v;
    }
    part[tid] = sum;
    __syncthreads();
    for (int off = 1; off < 1024; off <<= 1) {
        int v = 0;
        if (tid >= off) v = part[tid - off];
        __syncthreads();
        if (tid >= off) part[tid] += v;
        __syncthreads();
    }
    const int prev = (tid > 0) ? part[tid - 1] : 0;
#pragma unroll
    for (int k = 0; k < 5; ++k) {
        int idx = base + k;
        if (idx < VOCAB) offs[idx] = prev + local[k];
    }
    if (tid == 1023) offs[VOCAB] = part[1023];
}

__global__ void scatter_kernel(const int* __restrict__ x, const int* __restrict__ offs,
                               int* __restrict__ cursor, int* __restrict__ sorted_pk, int n) {
    int i = blockIdx.x * blockDim.x + threadIdx.x;
    int base = i * 4;
    if (base + 3 < n) {
        i32x4 v = *reinterpret_cast<const i32x4*>(x + base);
        int d;
        d = atomicAdd(&cursor[v.x], 1); sorted_pk[offs[v.x] + d] = ((base + 0) << 13) | v.x;
        d = atomicAdd(&cursor[v.y], 1); sorted_pk[offs[v.y] + d] = ((base + 1) << 13) | v.y;
        d = atomicAdd(&cursor[v.z], 1); sorted_pk[offs[v.z] + d] = ((base + 2) << 13) | v.z;
        d = atomicAdd(&cursor[v.w], 1); sorted_pk[offs[v.w] + d] = ((base + 3) << 13) | v.w;
    } else {
        for (int k = base; k < n; ++k) {
            int t = x[k];
            int d = atomicAdd(&cursor[t], 1);
            sorted_pk[offs[t] + d] = (k << 13) | t;
        }
    }
}

// ---------------------------------------------------------------------------
// Fused transpose + broadcast gather, double-buffered along the token axis.
// Block (cidx, tidx): W cols j0..j0+2047 (output cols) x tokens t0..t0+15,
// processed as two 8-token sub-tiles in 2 x 64 KiB LDS buffers (128 KiB,
// 1 block/CU, 16 waves). While sub0's stores run, sub1's global loads are
// in flight (issued into registers before the store loop) -> the load phase
// hides under the HBM-write-bound store phase.
// Store geometry is identical to R6 (best measured): one position per wave
// per iteration, 8KB contiguous NT write; pk prefetched one iter ahead.
// ---------------------------------------------------------------------------
__global__ __launch_bounds__(1024) void fused_gather_kernel(
        const float* __restrict__ W,
        const int* __restrict__ offs,
        const int* __restrict__ sorted_pk,
        float* __restrict__ out) {
    __shared__ float buf[2][TSUB][JCH];       // 2 x 64 KiB
    const int j0 = blockIdx.x * JCH;
    const int t0 = blockIdx.y * TTOK;
    const int jcnt = min(JCH, VOCAB - j0);    // 2048, 2048, 904
    const int tcnt = min(TTOK, VOCAB - t0);   // 16 or 8 (5000 = 312*16 + 8)
    const int nsub = tcnt >> 3;               // 2 or 1
    const int tid  = threadIdx.x;
    const int wid  = tid >> 6;                // 0..15
    const int lane = tid & 63;
    const int f0   = lane * 4;                // 0..252
    const int nfull    = jcnt >> 8;           // full 256-float chunks: 8 or 3
    const int remlanes = (jcnt & 255) >> 2;   // 0 or 34

    // chunk q = tid + k*1024 -> row jr = q>>1, 16B-piece c = q&1 (32B/row/sub)
    f32x4 r[4];

    auto issue_loads = [&](int ts) {
#pragma unroll
        for (int k = 0; k < 4; ++k) {
            const int q = tid + k * 1024;
            const int jr = q >> 1, c = q & 1;
            if (jr < jcnt)
                r[k] = *reinterpret_cast<const f32x4*>(
                    W + (size_t)(j0 + jr) * VOCAB + ts + c * 4);
        }
    };
    auto write_lds = [&](int sb) {
#pragma unroll
        for (int k = 0; k < 4; ++k) {
            const int q = tid + k * 1024;
            const int jr = q >> 1, c = q & 1;
            if (jr < jcnt) {
                buf[sb][c * 4 + 0][jr] = r[k].x;
                buf[sb][c * 4 + 1][jr] = r[k].y;
                buf[sb][c * 4 + 2][jr] = r[k].z;
                buf[sb][c * 4 + 3][jr] = r[k].w;
            }
        }
    };
    auto store_sub = [&](int sb, int ts) {
        const int begin = offs[ts];
        const int end   = offs[ts + TSUB];
        int i = begin + wid;
        if (i >= end) return;
        int pk = sorted_pk[i];
        for (;;) {
            const int inext = i + 16;
            int pk_next = 0;
            if (inext < end) pk_next = sorted_pk[inext];   // prefetch next pos

            const int p  = pk >> 13;
            const int tt = (pk & 8191) - ts;
            const float* __restrict__ srow = &buf[sb][tt][0];
            float* __restrict__ drow = out + (size_t)p * VOCAB + j0;
#pragma unroll
            for (int s = 0; s < 8; ++s) {
                if (s < nfull) {
                    f32x4 v = *reinterpret_cast<const f32x4*>(srow + f0 + s * 256);
                    __builtin_nontemporal_store(
                        v, reinterpret_cast<f32x4*>(drow + f0 + s * 256));
                }
            }
            if (lane < remlanes) {
                f32x4 v = *reinterpret_cast<const f32x4*>(srow + f0 + nfull * 256);
                __builtin_nontemporal_store(
                    v, reinterpret_cast<f32x4*>(drow + f0 + nfull * 256));
            }
            if (inext >= end) break;
            i = inext;
            pk = pk_next;
        }
    };

    // ---- pipeline ----
    issue_loads(t0);
    write_lds(0);
    __syncthreads();

    if (nsub == 2) {
        issue_loads(t0 + TSUB);   // sub1 loads in flight during sub0 stores
        store_sub(0, t0);
        write_lds(1);             // compiler-inserted waitcnt for the loads
        __syncthreads();
        store_sub(1, t0 + TSUB);
    } else {
        store_sub(0, t0);
    }
}

// ---------------------------------------------------------------------------
// Fallback (ws too small): direct column gather, correct but strided reads.
// ---------------------------------------------------------------------------
__global__ void gather_cols_kernel(const float* __restrict__ W,
                                   const int* __restrict__ idx,
                                   float* __restrict__ out) {
    const int p = blockIdx.x;
    const int token = idx[p];
    for (int v = threadIdx.x; v < VOCAB; v += blockDim.x)
        out[(size_t)p * VOCAB + v] = W[(size_t)v * VOCAB + token];
}

extern "C" void kernel_launch(void* const* d_in, const int* in_sizes, int n_in,
                              void* d_out, int out_size, void* d_ws, size_t ws_size,
                              hipStream_t stream) {
    const int*   x = (const int*)d_in[0];     // [B*T] token ids
    const float* W = (const float*)d_in[1];   // [VOCAB, VOCAB] fp32
    float* out = (float*)d_out;               // [B*T, VOCAB] fp32
    const int npos = in_sizes[0];             // 32768

    // ws layout: counts[V] | cursor[V] | offs[V+1] | sorted_pk[npos]
    int* counts = (int*)d_ws;
    int* cursor = counts + VOCAB;
    int* offs   = cursor + VOCAB;
    int* sorted = offs + VOCAB + 1;
    const size_t need = (size_t)(3 * VOCAB + 1 + npos) * sizeof(int);

    if (ws_size >= need) {
        hipMemsetAsync(counts, 0, (size_t)2 * VOCAB * sizeof(int), stream);
        const int n4blocks = ((npos + 3) / 4 + 255) / 256;
        hist_kernel<<<n4blocks, 256, 0, stream>>>(x, counts, npos);
        scan_kernel<<<1, 1024, 0, stream>>>(counts, offs);
        scatter_kernel<<<n4blocks, 256, 0, stream>>>(x, offs, cursor, sorted, npos);
        dim3 grid((VOCAB + JCH - 1) / JCH, (VOCAB + TTOK - 1) / TTOK);  // 3 x 313
        fused_gather_kernel<<<grid, 1024, 0, stream>>>(W, offs, sorted, out);
    } else {
        gather_cols_kernel<<<npos, 256, 0, stream>>>(W, x, out);
    }
}

// Round 12
// 189.835 us; speedup vs baseline: 1.0611x; 1.0220x over previous
//
#include <hip/hip_runtime.h>

#define VOCAB 5000
#define TTOK  16            // tokens per tile (64B of each W row)
#define JCH   2048          // output cols per chunk -> 8KB contiguous NT write/visit

typedef float f32x4 __attribute__((ext_vector_type(4)));
typedef int   i32x4 __attribute__((ext_vector_type(4)));

// ---------------------------------------------------------------------------
// Counting sort of positions by token id (packed: (pos << 13) | token).
// counts/cursor zeroed via hipMemsetAsync; hist/scatter int4-vectorized.
// ---------------------------------------------------------------------------
__global__ void hist_kernel(const int* __restrict__ x, int* __restrict__ counts, int n) {
    int i = blockIdx.x * blockDim.x + threadIdx.x;
    int base = i * 4;
    if (base + 3 < n) {
        i32x4 v = *reinterpret_cast<const i32x4*>(x + base);
        atomicAdd(&counts[v.x], 1);
        atomicAdd(&counts[v.y], 1);
        atomicAdd(&counts[v.z], 1);
        atomicAdd(&counts[v.w], 1);
    } else {
        for (int k = base; k < n; ++k) atomicAdd(&counts[x[k]], 1);
    }
}

// Single-block exclusive scan over VOCAB counters -> offs[0..VOCAB].
__global__ void scan_kernel(const int* __restrict__ counts, int* __restrict__ offs) {
    __shared__ int part[1024];
    const int tid = threadIdx.x;
    const int base = tid * 5;               // 1024*5 = 5120 >= 5000
    int local[5];
    int sum = 0;
#pragma unroll
    for (int k = 0; k < 5; ++k) {
        int idx = base + k;
        int v = (idx < VOCAB) ? counts[idx] : 0;
        local[k] = sum;
        sum += v;
    }
    part[tid] = sum;
    __syncthreads();
    for (int off = 1; off < 1024; off <<= 1) {
        int v = 0;
        if (tid >= off) v = part[tid - off];
        __syncthreads();
        if (tid >= off) part[tid] += v;
        __syncthreads();
    }
    const int prev = (tid > 0) ? part[tid - 1] : 0;
#pragma unroll
    for (int k = 0; k < 5; ++k) {
        int idx = base + k;
        if (idx < VOCAB) offs[idx] = prev + local[k];
    }
    if (tid == 1023) offs[VOCAB] = part[1023];
}

__global__ void scatter_kernel(const int* __restrict__ x, const int* __restrict__ offs,
                               int* __restrict__ cursor, int* __restrict__ sorted_pk, int n) {
    int i = blockIdx.x * blockDim.x + threadIdx.x;
    int base = i * 4;
    if (base + 3 < n) {
        i32x4 v = *reinterpret_cast<const i32x4*>(x + base);
        int d;
        d = atomicAdd(&cursor[v.x], 1); sorted_pk[offs[v.x] + d] = ((base + 0) << 13) | v.x;
        d = atomicAdd(&cursor[v.y], 1); sorted_pk[offs[v.y] + d] = ((base + 1) << 13) | v.y;
        d = atomicAdd(&cursor[v.z], 1); sorted_pk[offs[v.z] + d] = ((base + 2) << 13) | v.z;
        d = atomicAdd(&cursor[v.w], 1); sorted_pk[offs[v.w] + d] = ((base + 3) << 13) | v.w;
    } else {
        for (int k = base; k < n; ++k) {
            int t = x[k];
            int d = atomicAdd(&cursor[t], 1);
            sorted_pk[offs[t] + d] = (k << 13) | t;
        }
    }
}

// ---------------------------------------------------------------------------
// Fused transpose + broadcast gather (R6 geometry — measured best).
// Block (cidx, tidx): W cols j0..j0+2047 (output cols) x tokens t0..t0+15.
// LDS tile = 16 x 2048 floats = 128 KiB (1 block/CU, 16 waves).
// Load: coalesced 64B row-segments of W, read exactly once device-wide.
// Store: one position per wave per iteration, 8KB contiguous NT write
// (8 full 1KB wave-stores); pk prefetched one iteration ahead.
// NT stores: R6 vs R8 A/B showed NT worth ~18us on this write stream.
// Chunk-size curve (R5..R10): 2KB=199, 5KB=194, 8KB=186.7, 10KB=201 -> 8KB opt.
// ---------------------------------------------------------------------------
__global__ __launch_bounds__(1024) void fused_gather_kernel(
        const float* __restrict__ W,
        const int* __restrict__ offs,
        const int* __restrict__ sorted_pk,
        float* __restrict__ out) {
    __shared__ float tileT[TTOK][JCH];        // [token][col], 128 KiB
    const int j0 = blockIdx.x * JCH;
    const int t0 = blockIdx.y * TTOK;
    const int jcnt = min(JCH, VOCAB - j0);    // 2048, 2048, 904
    const int tcnt = min(TTOK, VOCAB - t0);   // 16 or 8
    const int tid = threadIdx.x;

    const int begin = offs[t0];
    const int end   = offs[t0 + tcnt];
    if (begin == end) return;                 // no positions use these tokens

    // --- load tile, transposed: tileT[token][col] ---
    const int nc4   = tcnt >> 2;              // f32x4 chunks across tokens: 4 or 2
    const int csh   = (tcnt == TTOK) ? 2 : 1;
    const int cmask = nc4 - 1;
    const int total = jcnt * nc4;
    for (int idx = tid; idx < total; idx += 1024) {
        const int jr = idx >> csh;
        const int c  = idx & cmask;
        f32x4 v = *reinterpret_cast<const f32x4*>(
            W + (size_t)(j0 + jr) * VOCAB + t0 + c * 4);
        tileT[c * 4 + 0][jr] = v.x;
        tileT[c * 4 + 1][jr] = v.y;
        tileT[c * 4 + 2][jr] = v.z;
        tileT[c * 4 + 3][jr] = v.w;
    }
    __syncthreads();

    // --- broadcast write: 16 waves, one position per wave per iteration ---
    const int wid  = tid >> 6;                // 0..15
    const int lane = tid & 63;
    const int f0 = lane * 4;                  // 0..252
    const int nfull    = jcnt >> 8;           // full 256-float chunks: 8 or 3
    const int remlanes = (jcnt & 255) >> 2;   // 0 or 34

    int i = begin + wid;
    if (i >= end) return;
    int pk = sorted_pk[i];
    for (;;) {
        const int inext = i + 16;
        int pk_next = 0;
        if (inext < end) pk_next = sorted_pk[inext];   // prefetch next position

        const int p  = pk >> 13;
        const int tt = (pk & 8191) - t0;
        const float* __restrict__ srow = &tileT[tt][0];
        float* __restrict__ drow = out + (size_t)p * VOCAB + j0;
#pragma unroll
        for (int s = 0; s < 8; ++s) {
            if (s < nfull) {
                f32x4 v = *reinterpret_cast<const f32x4*>(srow + f0 + s * 256);
                __builtin_nontemporal_store(
                    v, reinterpret_cast<f32x4*>(drow + f0 + s * 256));
            }
        }
        if (lane < remlanes) {
            f32x4 v = *reinterpret_cast<const f32x4*>(srow + f0 + nfull * 256);
            __builtin_nontemporal_store(
                v, reinterpret_cast<f32x4*>(drow + f0 + nfull * 256));
        }
        if (inext >= end) break;
        i = inext;
        pk = pk_next;
    }
}

// ---------------------------------------------------------------------------
// Fallback (ws too small): direct column gather, correct but strided reads.
// ---------------------------------------------------------------------------
__global__ void gather_cols_kernel(const float* __restrict__ W,
                                   const int* __restrict__ idx,
                                   float* __restrict__ out) {
    const int p = blockIdx.x;
    const int token = idx[p];
    for (int v = threadIdx.x; v < VOCAB; v += blockDim.x)
        out[(size_t)p * VOCAB + v] = W[(size_t)v * VOCAB + token];
}

extern "C" void kernel_launch(void* const* d_in, const int* in_sizes, int n_in,
                              void* d_out, int out_size, void* d_ws, size_t ws_size,
                              hipStream_t stream) {
    const int*   x = (const int*)d_in[0];     // [B*T] token ids
    const float* W = (const float*)d_in[1];   // [VOCAB, VOCAB] fp32
    float* out = (float*)d_out;               // [B*T, VOCAB] fp32
    const int npos = in_sizes[0];             // 32768

    // ws layout: counts[V] | cursor[V] | offs[V+1] | sorted_pk[npos]
    int* counts = (int*)d_ws;
    int* cursor = counts + VOCAB;
    int* offs   = cursor + VOCAB;
    int* sorted = offs + VOCAB + 1;
    const size_t need = (size_t)(3 * VOCAB + 1 + npos) * sizeof(int);

    if (ws_size >= need) {
        hipMemsetAsync(counts, 0, (size_t)2 * VOCAB * sizeof(int), stream);
        const int n4blocks = ((npos + 3) / 4 + 255) / 256;
        hist_kernel<<<n4blocks, 256, 0, stream>>>(x, counts, npos);
        scan_kernel<<<1, 1024, 0, stream>>>(counts, offs);
        scatter_kernel<<<n4blocks, 256, 0, stream>>>(x, offs, cursor, sorted, npos);
        dim3 grid((VOCAB + JCH - 1) / JCH, (VOCAB + TTOK - 1) / TTOK);  // 3 x 313
        fused_gather_kernel<<<grid, 1024, 0, stream>>>(W, offs, sorted, out);
    } else {
        gather_cols_kernel<<<npos, 256, 0, stream>>>(W, x, out);
    }
}